// Round 16
// baseline (860.005 us; speedup 1.0000x reference)
//
#include <hip/hip_runtime.h>
#include <hip/hip_bf16.h>

typedef unsigned int   u32;
typedef unsigned short u16;
typedef _Float16       f16;
typedef __attribute__((ext_vector_type(2))) _Float16 f16x2;
typedef __attribute__((ext_vector_type(8))) _Float16 f16x8;
typedef __attribute__((ext_vector_type(4))) float    f32x4;
typedef __attribute__((ext_vector_type(4))) u32      u32x4;

#define T_STEPS 512
#define BATCH   256
#define O_IN    720
#define KPAD    736      // 720 padded to mult of 32 (zero pad in wxt)
#define HID     128
#define G4      512      // 4*HID
// d_out layout (floats): am[512] | std[2] | value[256] | hT[32768] | cT[32768]
#define OUT_STD 512
#define OUT_VAL 514
#define OUT_HT  770
#define OUT_CT  33538

// ws layout (bytes); requires ws_size >= ~135 MB
static const unsigned long long XW_OFF  = 0ull;          // f16 [131072][512] = 134217728 B
static const unsigned long long WXT_OFF = 134217728ull;  // f16 [512][736]    = 753664 B

// raw transcendental asm (R11-validated): v_exp_f32 = 2^x; v_rcp_f32 ~1ulp.
__device__ inline float exp2raw(float x){
  float r; asm("v_exp_f32 %0, %1" : "=v"(r) : "v"(x)); return r;
}
__device__ inline float rcpraw(float x){
  float r; asm("v_rcp_f32 %0, %1" : "=v"(r) : "v"(x)); return r;
}
__device__ inline float tanhfast(float x){
  return fmaf(2.f, rcpraw(1.0f + exp2raw(-2.88539008f * x)), -1.f);
}

// f16-pair dot2, inline asm (builtin broken: R2/R8; asm proven R9-R15).
__device__ inline float dot2f(u32 a, u32 b, float c){
  float d;
  asm("v_dot2_f32_f16 %0, %1, %2, %3" : "=v"(d) : "v"(a), "v"(b), "v"(c));
  return d;
}

// DPP quad_perm (VALU pipe; ctrls 177/78/0/85/170/255 HW-proven in R11-pass).
#define DPPF(x, ctrl) \
  __uint_as_float((u32)__builtin_amdgcn_update_dpp(0, (int)__float_as_uint(x), (ctrl), 0xF, 0xF, false))

// R11 h layout: f16, quarter q (32 halves = 64B) at byte q*80 (16B pad/quarter).
#define HQ_STRIDE 80
#define H_BYTES   (4*HQ_STRIDE)
#define HW_OFF(j) (((j)>>5)*HQ_STRIDE + ((j)&31)*2)

// ---------------- K0: Wx (720,512) f32 -> Wx^T f16 [512][736] zero-padded ----------------
__global__ void k_pack_wxt(const float* __restrict__ Wx, u16* __restrict__ wxt){
  const int n = blockIdx.x;               // 512 blocks
  for (int k = threadIdx.x; k < KPAD; k += 256){
    float v = (k < O_IN) ? Wx[(size_t)k * G4 + n] : 0.f;
    wxt[(size_t)n * KPAD + k] = __builtin_bit_cast(u16, (f16)v);
  }
}

// ---------------- K1 v2: xW = x @ Wx — 128x128 block, 4 waves/SIMD ------------------------
// R16: occupancy fix. Wave tile 32x128 (mf=2): acc 64 VGPR, total ~110-130 -> <=128 tier
// = 4 waves/SIMD (was 2 at 64x128/~200 VGPR). Same proven K-pipeline + epilogue mapping.
// Grid 4096 = 1024 mb x 4 nb; bijective XCD swizzle (4096 = 8*512).
__global__ __launch_bounds__(256, 4) void k_gemm(const float* __restrict__ x,
                                                 const u16* __restrict__ wxt,
                                                 u16* __restrict__ xw)
{
  const int l  = threadIdx.x & 63;
  const int w  = threadIdx.x >> 6;
  const int lr = l & 15;
  const int lk = l >> 4;
  const u32 L  = (blockIdx.x & 7u) * 512u + (blockIdx.x >> 3);
  const u32 mb = L >> 2, nb = L & 3u;
  const u32 M0 = mb * 128u + (u32)w * 32u;
  const u32 N0 = nb * 128u;

  const float* ax[2];
  const u16*   bx[8];
#pragma unroll
  for (int mf = 0; mf < 2; ++mf)
    ax[mf] = x + (unsigned long long)(M0 + mf*16 + lr) * O_IN + lk*8;
#pragma unroll
  for (int nf = 0; nf < 8; ++nf)
    bx[nf] = wxt + (unsigned long long)(N0 + nf*16 + lr) * KPAD + lk*8;

  f32x4 acc[2][8];
#pragma unroll
  for (int mf = 0; mf < 2; ++mf)
#pragma unroll
    for (int nf = 0; nf < 8; ++nf)
      acc[mf][nf] = (f32x4){0.f, 0.f, 0.f, 0.f};

  f32x4 a0[2][2];
  f16x8 aF[2], bF[8];

#pragma unroll
  for (int mf = 0; mf < 2; ++mf){
    a0[mf][0] = *(const f32x4*)(ax[mf]);
    a0[mf][1] = *(const f32x4*)(ax[mf] + 4);
  }
#pragma unroll
  for (int nf = 0; nf < 8; ++nf)
    bF[nf] = *(const f16x8*)(bx[nf]);
#pragma unroll
  for (int mf = 0; mf < 2; ++mf){
    f32x4 lo = a0[mf][0], hi = a0[mf][1];
    f16x8 v; v[0]=(f16)lo.x; v[1]=(f16)lo.y; v[2]=(f16)lo.z; v[3]=(f16)lo.w;
             v[4]=(f16)hi.x; v[5]=(f16)hi.y; v[6]=(f16)hi.z; v[7]=(f16)hi.w;
    aF[mf] = v;
  }

  for (int kc = 0; kc < 22; ++kc){
    if (kc < 21){                               // issue next A (long-latency) early
#pragma unroll
      for (int mf = 0; mf < 2; ++mf){
        a0[mf][0] = *(const f32x4*)(ax[mf] + (kc+1)*32);
        a0[mf][1] = *(const f32x4*)(ax[mf] + (kc+1)*32 + 4);
      }
    }
#pragma unroll
    for (int nf = 0; nf < 8; ++nf){
#pragma unroll
      for (int mf = 0; mf < 2; ++mf)
        acc[mf][nf] = __builtin_amdgcn_mfma_f32_16x16x32_f16(aF[mf], bF[nf], acc[mf][nf], 0, 0, 0);
      if (kc < 21)                              // reload B right after last use (L2-hit)
        bF[nf] = *(const f16x8*)(bx[nf] + (kc+1)*32);
    }
    if (kc < 21){
#pragma unroll
      for (int mf = 0; mf < 2; ++mf){
        f32x4 lo = a0[mf][0], hi = a0[mf][1];
        f16x8 v; v[0]=(f16)lo.x; v[1]=(f16)lo.y; v[2]=(f16)lo.z; v[3]=(f16)lo.w;
                 v[4]=(f16)hi.x; v[5]=(f16)hi.y; v[6]=(f16)hi.z; v[7]=(f16)hi.w;
        aF[mf] = v;
      }
    }
  }

  { // K tail: k = 704..719 valid (lanes lk<2), wxt zero-padded to 736
    f16x8 aT[2];
#pragma unroll
    for (int mf = 0; mf < 2; ++mf) aT[mf] = (f16x8)(f16)0.f;
    if (lk < 2){
#pragma unroll
      for (int mf = 0; mf < 2; ++mf){
        f32x4 lo = *(const f32x4*)(ax[mf] + 704);
        f32x4 hi = *(const f32x4*)(ax[mf] + 708);
        f16x8 v; v[0]=(f16)lo.x; v[1]=(f16)lo.y; v[2]=(f16)lo.z; v[3]=(f16)lo.w;
                 v[4]=(f16)hi.x; v[5]=(f16)hi.y; v[6]=(f16)hi.z; v[7]=(f16)hi.w;
        aT[mf] = v;
      }
    }
#pragma unroll
    for (int nf = 0; nf < 8; ++nf){
      f16x8 bT = *(const f16x8*)(bx[nf] + 704);
#pragma unroll
      for (int mf = 0; mf < 2; ++mf)
        acc[mf][nf] = __builtin_amdgcn_mfma_f32_16x16x32_f16(aT[mf], bT, acc[mf][nf], 0, 0, 0);
    }
  }

  // epilogue: D row = lk*4 + r, col = lr (proven mapping)
#pragma unroll
  for (int mf = 0; mf < 2; ++mf){
    const u32 rowb = M0 + mf*16 + lk*4;
#pragma unroll
    for (int nf = 0; nf < 8; ++nf){
      const u32 col = N0 + nf*16 + lr;
#pragma unroll
      for (int r = 0; r < 4; ++r)
        xw[(unsigned long long)(rowb + r) * G4 + col] = __builtin_bit_cast(u16, (f16)acc[mf][nf][r]);
    }
  }
}

// ---------------- K2: LSTM scan — VERBATIM R11 (proven: PASS 0.0078125, 459us) ------------
__global__ __attribute__((amdgpu_flat_work_group_size(512,512), amdgpu_waves_per_eu(2,2)))
void k_rnn(
    const u16* __restrict__ xw, const float* __restrict__ Wh,
    const float* __restrict__ h0, const float* __restrict__ c0,
    const float* __restrict__ bvec,
    const float* __restrict__ Wa1, const float* __restrict__ ba1,
    const float* __restrict__ Wa2, const float* __restrict__ ba2,
    const float* __restrict__ Wc1, const float* __restrict__ bc1,
    const float* __restrict__ Wc2, const float* __restrict__ bc2,
    const float* __restrict__ log_std, float* __restrict__ out)
{
  const int b = blockIdx.x;
  const int t = threadIdx.x;          // 0..511
  const int j = t >> 2;               // gate/h column 0..127
  const int q = t & 3;                // k-quarter & gate slot

  __shared__ __align__(16) char hbuf[2][H_BYTES];  // h f16, padded quarters, double-buffered
  __shared__ __align__(16) float hf[HID];          // final h fp32 (heads)
  __shared__ float hid[256];

  // ---- weights: wgN[m] = f16x2{ Wh[32q+2m][j+128N], Wh[32q+2m+1][j+128N] } ----
  u32 wg0[16], wg1[16], wg2[16], wg3[16];
#pragma unroll
  for (int m = 0; m < 16; ++m){
    const u32 kb = (u32)(32*q + 2*m) * G4 + (u32)j;
    f16x2 p;
    p[0]=(f16)Wh[kb      ]; p[1]=(f16)Wh[kb+G4      ]; wg0[m]=__builtin_bit_cast(u32,p);
    p[0]=(f16)Wh[kb+128  ]; p[1]=(f16)Wh[kb+G4+128  ]; wg1[m]=__builtin_bit_cast(u32,p);
    p[0]=(f16)Wh[kb+256  ]; p[1]=(f16)Wh[kb+G4+256  ]; wg2[m]=__builtin_bit_cast(u32,p);
    p[0]=(f16)Wh[kb+384  ]; p[1]=(f16)Wh[kb+G4+384  ]; wg3[m]=__builtin_bit_cast(u32,p);
  }
  // pin: opaque identity so the scheduler cannot sink the loads back into the loop
#pragma unroll
  for (int m = 0; m < 16; ++m){
    asm volatile("" : "+v"(wg0[m]));
    asm volatile("" : "+v"(wg1[m]));
    asm volatile("" : "+v"(wg2[m]));
    asm volatile("" : "+v"(wg3[m]));
  }
  const float bb = bvec[j + 128*q];   // bias for this thread's gate col

  // branchless activation constants: gate q==2 -> tanh(g)=2*sig(2g)-1, else sigmoid
  const float kexp  = (q == 2) ? -2.88539008f : -1.44269504f;
  const float postm = (q == 2) ? 2.f : 1.f;
  const float posta = (q == 2) ? -1.f : 0.f;

  // ---- state (replicated across the 4 partner lanes) ----
  float cs = c0[b*HID + j];
  float hv = h0[b*HID + j];
  if (q == 0)
    *(u16*)(hbuf[0] + HW_OFF(j)) = __builtin_bit_cast(u16, (f16)hv);
  __syncthreads();

  const u16* xp = xw + (u32)b * G4 + (u32)(j + 128*q);
  float xc  = (float)__builtin_bit_cast(f16, xp[0]) + bb;
  float xn1 = (T_STEPS > 1) ? (float)__builtin_bit_cast(f16, xp[131072u]) + bb : 0.f;

  for (int s = 0; s < T_STEPS; ++s){
    const char* hq = hbuf[s & 1] + q * HQ_STRIDE;

    float xn2 = 0.f;
    if (s + 2 < T_STEPS)
      xn2 = (float)__builtin_bit_cast(f16, xp[(u32)(s+2) * 131072u]) + bb;

    float p0 = 0.f, p1 = 0.f, p2 = 0.f, p3 = 0.f;
#pragma unroll
    for (int it = 0; it < 4; ++it){
      u32x4 hh = *(const u32x4*)(hq + it*16);    // 4 distinct addrs/wave, bank-disjoint
#pragma unroll
      for (int z = 0; z < 4; ++z){
        p0 = dot2f(hh[z], wg0[4*it+z], p0);
        p1 = dot2f(hh[z], wg1[4*it+z], p1);
        p2 = dot2f(hh[z], wg2[4*it+z], p2);
        p3 = dot2f(hh[z], wg3[4*it+z], p3);
      }
    }
    // reduce across the 4 partner lanes via DPP quad_perm (VALU, no DS traffic)
    p0 += DPPF(p0, 177);  p1 += DPPF(p1, 177);   // xor 1
    p2 += DPPF(p2, 177);  p3 += DPPF(p3, 177);
    p0 += DPPF(p0, 78);   p1 += DPPF(p1, 78);    // xor 2
    p2 += DPPF(p2, 78);   p3 += DPPF(p3, 78);

    // this lane activates gate q of col j: mul -> exp -> add -> rcp -> fma
    float gsum = (q == 0) ? p0 : (q == 1) ? p1 : (q == 2) ? p2 : p3;
    float gval = gsum + xc;
    float r    = rcpraw(1.0f + exp2raw(kexp * gval));
    float av   = fmaf(postm, r, posta);

    // gather the 4 activated gates from partner lanes (DPP quad broadcasts)
    float ai = DPPF(av, 0);     // lane lbase+0
    float af = DPPF(av, 85);    // lane lbase+1
    float ag = DPPF(av, 170);   // lane lbase+2
    float ao = DPPF(av, 255);   // lane lbase+3

    cs = af * cs + ai * ag;
    hv = ao * tanhfast(cs);
    if (q == 0)
      *(u16*)(hbuf[(s & 1) ^ 1] + HW_OFF(j)) = __builtin_bit_cast(u16, (f16)hv);
    __syncthreads();                 // h[s+1] visible; prior-buffer reads all done
    xc = xn1; xn1 = xn2;
  }

  if (q == 0){                       // exact fp32 state out
    out[OUT_HT + b*HID + j] = hv;
    out[OUT_CT + b*HID + j] = cs;
    hf[j] = hv;
  }
  __syncthreads();

  if (t < 256){ // heads hidden, fp32: t<128 -> actor col t; else critic col t-128
    const float* W = (t < HID) ? Wa1 : Wc1;
    const int col  = t & (HID - 1);
    const f32x4* hp4 = (const f32x4*)hf;
    float a0 = 0.f, a1 = 0.f, a2 = 0.f, a3 = 0.f;
#pragma unroll
    for (int qq = 0; qq < 32; ++qq){
      f32x4 hh = hp4[qq];
      a0 = fmaf(hh.x, W[(u32)(4*qq+0)*HID + col], a0);
      a1 = fmaf(hh.y, W[(u32)(4*qq+1)*HID + col], a1);
      a2 = fmaf(hh.z, W[(u32)(4*qq+2)*HID + col], a2);
      a3 = fmaf(hh.w, W[(u32)(4*qq+3)*HID + col], a3);
    }
    float a = (a0 + a1) + (a2 + a3);
    hid[t] = (t < HID) ? tanhfast(a + ba1[col]) : tanhfast(a + bc1[col]);
  }
  __syncthreads();

  {
    const int wv = t >> 6, lane = t & 63;
    float p = 0.f;
    if (wv == 0)      p = hid[lane]     * Wa2[lane*2]   + hid[lane+64]     * Wa2[(lane+64)*2];
    else if (wv == 1) p = hid[lane]     * Wa2[lane*2+1] + hid[lane+64]     * Wa2[(lane+64)*2+1];
    else if (wv == 2) p = hid[128+lane] * Wc2[lane]     + hid[128+lane+64] * Wc2[lane+64];
#pragma unroll
    for (int off = 32; off > 0; off >>= 1) p += __shfl_down(p, off);
    if (lane == 0){
      if (wv == 0) out[b*2 + 0]   = p + ba2[0];
      if (wv == 1) out[b*2 + 1]   = p + ba2[1];
      if (wv == 2) out[OUT_VAL+b] = p + bc2[0];
    }
    if (b == 0 && wv == 3 && lane < 2) out[OUT_STD + lane] = expf(log_std[lane]);
  }
}

extern "C" void kernel_launch(void* const* d_in, const int* in_sizes, int n_in,
                              void* d_out, int out_size, void* d_ws, size_t ws_size,
                              hipStream_t stream)
{
  (void)in_sizes; (void)n_in; (void)out_size; (void)ws_size;
  const float* x    = (const float*)d_in[0];
  const float* h0   = (const float*)d_in[1];
  const float* c0   = (const float*)d_in[2];
  const float* Wx   = (const float*)d_in[3];
  const float* Wh   = (const float*)d_in[4];
  const float* bv   = (const float*)d_in[5];
  const float* Wa1  = (const float*)d_in[6];
  const float* ba1  = (const float*)d_in[7];
  const float* Wa2  = (const float*)d_in[8];
  const float* ba2  = (const float*)d_in[9];
  const float* lstd = (const float*)d_in[10];
  const float* Wc1  = (const float*)d_in[11];
  const float* bc1  = (const float*)d_in[12];
  const float* Wc2  = (const float*)d_in[13];
  const float* bc2  = (const float*)d_in[14];
  float* out = (float*)d_out;
  char*  ws  = (char*)d_ws;

  u16* xw  = (u16*)(ws + XW_OFF);
  u16* wxt = (u16*)(ws + WXT_OFF);

  k_pack_wxt<<<dim3(512),  dim3(256), 0, stream>>>(Wx, wxt);
  k_gemm<<<dim3(4096),     dim3(256), 0, stream>>>(x, wxt, xw);
  k_rnn<<<dim3(256),       dim3(512), 0, stream>>>(xw, Wh, h0, c0, bv,
                                                   Wa1, ba1, Wa2, ba2, Wc1, bc1, Wc2, bc2,
                                                   lstd, out);
}

// Round 17
// 848.214 us; speedup vs baseline: 1.0139x; 1.0139x over previous
//
#include <hip/hip_runtime.h>
#include <hip/hip_bf16.h>

typedef unsigned int   u32;
typedef unsigned short u16;
typedef _Float16       f16;
typedef __attribute__((ext_vector_type(2))) _Float16 f16x2;
typedef __attribute__((ext_vector_type(8))) _Float16 f16x8;
typedef __attribute__((ext_vector_type(4))) float    f32x4;
typedef __attribute__((ext_vector_type(4))) u32      u32x4;

#define T_STEPS 512
#define BATCH   256
#define O_IN    720
#define KPAD    736      // 720 padded to mult of 32 (zero pad in wxt)
#define HID     128
#define G4      512      // 4*HID
// d_out layout (floats): am[512] | std[2] | value[256] | hT[32768] | cT[32768]
#define OUT_STD 512
#define OUT_VAL 514
#define OUT_HT  770
#define OUT_CT  33538

// ws layout (bytes); requires ws_size >= ~135 MB
static const unsigned long long XW_OFF  = 0ull;          // f16 [131072][512] = 134217728 B
static const unsigned long long WXT_OFF = 134217728ull;  // f16 [512][736]    = 753664 B

// raw transcendental asm (R11-validated): v_exp_f32 = 2^x; v_rcp_f32 ~1ulp.
__device__ inline float exp2raw(float x){
  float r; asm("v_exp_f32 %0, %1" : "=v"(r) : "v"(x)); return r;
}
__device__ inline float rcpraw(float x){
  float r; asm("v_rcp_f32 %0, %1" : "=v"(r) : "v"(x)); return r;
}
__device__ inline float tanhfast(float x){
  return fmaf(2.f, rcpraw(1.0f + exp2raw(-2.88539008f * x)), -1.f);
}

// f16-pair dot2, inline asm (builtin broken: R2/R8; asm proven R9-R16).
__device__ inline float dot2f(u32 a, u32 b, float c){
  float d;
  asm("v_dot2_f32_f16 %0, %1, %2, %3" : "=v"(d) : "v"(a), "v"(b), "v"(c));
  return d;
}

// DPP quad_perm (VALU pipe; ctrls 177/78/0/85/170/255 HW-proven in R11-pass).
#define DPPF(x, ctrl) \
  __uint_as_float((u32)__builtin_amdgcn_update_dpp(0, (int)__float_as_uint(x), (ctrl), 0xF, 0xF, false))

// R11 h layout: f16, quarter q (32 halves = 64B) at byte q*80 (16B pad/quarter).
#define HQ_STRIDE 80
#define H_BYTES   (4*HQ_STRIDE)
#define HW_OFF(j) (((j)>>5)*HQ_STRIDE + ((j)&31)*2)

// ---------------- K0: Wx (720,512) f32 -> Wx^T f16 [512][736] zero-padded ----------------
__global__ void k_pack_wxt(const float* __restrict__ Wx, u16* __restrict__ wxt){
  const int n = blockIdx.x;               // 512 blocks
  for (int k = threadIdx.x; k < KPAD; k += 256){
    float v = (k < O_IN) ? Wx[(size_t)k * G4 + n] : 0.f;
    wxt[(size_t)n * KPAD + k] = __builtin_bit_cast(u16, (f16)v);
  }
}

// ---------------- K1 v3: xW = x @ Wx — 128x128 block, waves_per_eu(3,3) ------------------
// R16 failed: __launch_bounds__(256,4) let the allocator chase the 64-reg tier and SPILL
// the accumulators (VGPR=64, 463us, MfmaUtil 8.7%). R17: pin the tier with the attribute
// that actually worked in R10 — waves_per_eu(3,3) => 170-reg budget >= ~150 needed,
// 3 waves/SIMD (1.5x the old 64x128 kernel's latency hiding).
__global__ __attribute__((amdgpu_flat_work_group_size(256,256), amdgpu_waves_per_eu(3,3)))
void k_gemm(const float* __restrict__ x,
            const u16* __restrict__ wxt,
            u16* __restrict__ xw)
{
  const int l  = threadIdx.x & 63;
  const int w  = threadIdx.x >> 6;
  const int lr = l & 15;
  const int lk = l >> 4;
  const u32 L  = (blockIdx.x & 7u) * 512u + (blockIdx.x >> 3);
  const u32 mb = L >> 2, nb = L & 3u;
  const u32 M0 = mb * 128u + (u32)w * 32u;
  const u32 N0 = nb * 128u;

  const float* ax[2];
  const u16*   bx[8];
#pragma unroll
  for (int mf = 0; mf < 2; ++mf)
    ax[mf] = x + (unsigned long long)(M0 + mf*16 + lr) * O_IN + lk*8;
#pragma unroll
  for (int nf = 0; nf < 8; ++nf)
    bx[nf] = wxt + (unsigned long long)(N0 + nf*16 + lr) * KPAD + lk*8;

  f32x4 acc[2][8];
#pragma unroll
  for (int mf = 0; mf < 2; ++mf)
#pragma unroll
    for (int nf = 0; nf < 8; ++nf)
      acc[mf][nf] = (f32x4){0.f, 0.f, 0.f, 0.f};

  f32x4 a0[2][2];
  f16x8 aF[2], bF[8];

#pragma unroll
  for (int mf = 0; mf < 2; ++mf){
    a0[mf][0] = *(const f32x4*)(ax[mf]);
    a0[mf][1] = *(const f32x4*)(ax[mf] + 4);
  }
#pragma unroll
  for (int nf = 0; nf < 8; ++nf)
    bF[nf] = *(const f16x8*)(bx[nf]);
#pragma unroll
  for (int mf = 0; mf < 2; ++mf){
    f32x4 lo = a0[mf][0], hi = a0[mf][1];
    f16x8 v; v[0]=(f16)lo.x; v[1]=(f16)lo.y; v[2]=(f16)lo.z; v[3]=(f16)lo.w;
             v[4]=(f16)hi.x; v[5]=(f16)hi.y; v[6]=(f16)hi.z; v[7]=(f16)hi.w;
    aF[mf] = v;
  }

  for (int kc = 0; kc < 22; ++kc){
    if (kc < 21){                               // issue next A (long-latency) early
#pragma unroll
      for (int mf = 0; mf < 2; ++mf){
        a0[mf][0] = *(const f32x4*)(ax[mf] + (kc+1)*32);
        a0[mf][1] = *(const f32x4*)(ax[mf] + (kc+1)*32 + 4);
      }
    }
#pragma unroll
    for (int nf = 0; nf < 8; ++nf){
#pragma unroll
      for (int mf = 0; mf < 2; ++mf)
        acc[mf][nf] = __builtin_amdgcn_mfma_f32_16x16x32_f16(aF[mf], bF[nf], acc[mf][nf], 0, 0, 0);
      if (kc < 21)                              // reload B right after last use (L2-hit)
        bF[nf] = *(const f16x8*)(bx[nf] + (kc+1)*32);
    }
    if (kc < 21){
#pragma unroll
      for (int mf = 0; mf < 2; ++mf){
        f32x4 lo = a0[mf][0], hi = a0[mf][1];
        f16x8 v; v[0]=(f16)lo.x; v[1]=(f16)lo.y; v[2]=(f16)lo.z; v[3]=(f16)lo.w;
                 v[4]=(f16)hi.x; v[5]=(f16)hi.y; v[6]=(f16)hi.z; v[7]=(f16)hi.w;
        aF[mf] = v;
      }
    }
  }

  { // K tail: k = 704..719 valid (lanes lk<2), wxt zero-padded to 736
    f16x8 aT[2];
#pragma unroll
    for (int mf = 0; mf < 2; ++mf) aT[mf] = (f16x8)(f16)0.f;
    if (lk < 2){
#pragma unroll
      for (int mf = 0; mf < 2; ++mf){
        f32x4 lo = *(const f32x4*)(ax[mf] + 704);
        f32x4 hi = *(const f32x4*)(ax[mf] + 708);
        f16x8 v; v[0]=(f16)lo.x; v[1]=(f16)lo.y; v[2]=(f16)lo.z; v[3]=(f16)lo.w;
                 v[4]=(f16)hi.x; v[5]=(f16)hi.y; v[6]=(f16)hi.z; v[7]=(f16)hi.w;
        aT[mf] = v;
      }
    }
#pragma unroll
    for (int nf = 0; nf < 8; ++nf){
      f16x8 bT = *(const f16x8*)(bx[nf] + 704);
#pragma unroll
      for (int mf = 0; mf < 2; ++mf)
        acc[mf][nf] = __builtin_amdgcn_mfma_f32_16x16x32_f16(aT[mf], bT, acc[mf][nf], 0, 0, 0);
    }
  }

  // epilogue: D row = lk*4 + r, col = lr (proven mapping)
#pragma unroll
  for (int mf = 0; mf < 2; ++mf){
    const u32 rowb = M0 + mf*16 + lk*4;
#pragma unroll
    for (int nf = 0; nf < 8; ++nf){
      const u32 col = N0 + nf*16 + lr;
#pragma unroll
      for (int r = 0; r < 4; ++r)
        xw[(unsigned long long)(rowb + r) * G4 + col] = __builtin_bit_cast(u16, (f16)acc[mf][nf][r]);
    }
  }
}

// ---------------- K2: LSTM scan — VERBATIM R11 (proven: PASS 0.0078125, ~390-459us) -------
__global__ __attribute__((amdgpu_flat_work_group_size(512,512), amdgpu_waves_per_eu(2,2)))
void k_rnn(
    const u16* __restrict__ xw, const float* __restrict__ Wh,
    const float* __restrict__ h0, const float* __restrict__ c0,
    const float* __restrict__ bvec,
    const float* __restrict__ Wa1, const float* __restrict__ ba1,
    const float* __restrict__ Wa2, const float* __restrict__ ba2,
    const float* __restrict__ Wc1, const float* __restrict__ bc1,
    const float* __restrict__ Wc2, const float* __restrict__ bc2,
    const float* __restrict__ log_std, float* __restrict__ out)
{
  const int b = blockIdx.x;
  const int t = threadIdx.x;          // 0..511
  const int j = t >> 2;               // gate/h column 0..127
  const int q = t & 3;                // k-quarter & gate slot

  __shared__ __align__(16) char hbuf[2][H_BYTES];  // h f16, padded quarters, double-buffered
  __shared__ __align__(16) float hf[HID];          // final h fp32 (heads)
  __shared__ float hid[256];

  // ---- weights: wgN[m] = f16x2{ Wh[32q+2m][j+128N], Wh[32q+2m+1][j+128N] } ----
  u32 wg0[16], wg1[16], wg2[16], wg3[16];
#pragma unroll
  for (int m = 0; m < 16; ++m){
    const u32 kb = (u32)(32*q + 2*m) * G4 + (u32)j;
    f16x2 p;
    p[0]=(f16)Wh[kb      ]; p[1]=(f16)Wh[kb+G4      ]; wg0[m]=__builtin_bit_cast(u32,p);
    p[0]=(f16)Wh[kb+128  ]; p[1]=(f16)Wh[kb+G4+128  ]; wg1[m]=__builtin_bit_cast(u32,p);
    p[0]=(f16)Wh[kb+256  ]; p[1]=(f16)Wh[kb+G4+256  ]; wg2[m]=__builtin_bit_cast(u32,p);
    p[0]=(f16)Wh[kb+384  ]; p[1]=(f16)Wh[kb+G4+384  ]; wg3[m]=__builtin_bit_cast(u32,p);
  }
  // pin: opaque identity so the scheduler cannot sink the loads back into the loop
#pragma unroll
  for (int m = 0; m < 16; ++m){
    asm volatile("" : "+v"(wg0[m]));
    asm volatile("" : "+v"(wg1[m]));
    asm volatile("" : "+v"(wg2[m]));
    asm volatile("" : "+v"(wg3[m]));
  }
  const float bb = bvec[j + 128*q];   // bias for this thread's gate col

  // branchless activation constants: gate q==2 -> tanh(g)=2*sig(2g)-1, else sigmoid
  const float kexp  = (q == 2) ? -2.88539008f : -1.44269504f;
  const float postm = (q == 2) ? 2.f : 1.f;
  const float posta = (q == 2) ? -1.f : 0.f;

  // ---- state (replicated across the 4 partner lanes) ----
  float cs = c0[b*HID + j];
  float hv = h0[b*HID + j];
  if (q == 0)
    *(u16*)(hbuf[0] + HW_OFF(j)) = __builtin_bit_cast(u16, (f16)hv);
  __syncthreads();

  const u16* xp = xw + (u32)b * G4 + (u32)(j + 128*q);
  float xc  = (float)__builtin_bit_cast(f16, xp[0]) + bb;
  float xn1 = (T_STEPS > 1) ? (float)__builtin_bit_cast(f16, xp[131072u]) + bb : 0.f;

  for (int s = 0; s < T_STEPS; ++s){
    const char* hq = hbuf[s & 1] + q * HQ_STRIDE;

    float xn2 = 0.f;
    if (s + 2 < T_STEPS)
      xn2 = (float)__builtin_bit_cast(f16, xp[(u32)(s+2) * 131072u]) + bb;

    float p0 = 0.f, p1 = 0.f, p2 = 0.f, p3 = 0.f;
#pragma unroll
    for (int it = 0; it < 4; ++it){
      u32x4 hh = *(const u32x4*)(hq + it*16);    // 4 distinct addrs/wave, bank-disjoint
#pragma unroll
      for (int z = 0; z < 4; ++z){
        p0 = dot2f(hh[z], wg0[4*it+z], p0);
        p1 = dot2f(hh[z], wg1[4*it+z], p1);
        p2 = dot2f(hh[z], wg2[4*it+z], p2);
        p3 = dot2f(hh[z], wg3[4*it+z], p3);
      }
    }
    // reduce across the 4 partner lanes via DPP quad_perm (VALU, no DS traffic)
    p0 += DPPF(p0, 177);  p1 += DPPF(p1, 177);   // xor 1
    p2 += DPPF(p2, 177);  p3 += DPPF(p3, 177);
    p0 += DPPF(p0, 78);   p1 += DPPF(p1, 78);    // xor 2
    p2 += DPPF(p2, 78);   p3 += DPPF(p3, 78);

    // this lane activates gate q of col j: mul -> exp -> add -> rcp -> fma
    float gsum = (q == 0) ? p0 : (q == 1) ? p1 : (q == 2) ? p2 : p3;
    float gval = gsum + xc;
    float r    = rcpraw(1.0f + exp2raw(kexp * gval));
    float av   = fmaf(postm, r, posta);

    // gather the 4 activated gates from partner lanes (DPP quad broadcasts)
    float ai = DPPF(av, 0);     // lane lbase+0
    float af = DPPF(av, 85);    // lane lbase+1
    float ag = DPPF(av, 170);   // lane lbase+2
    float ao = DPPF(av, 255);   // lane lbase+3

    cs = af * cs + ai * ag;
    hv = ao * tanhfast(cs);
    if (q == 0)
      *(u16*)(hbuf[(s & 1) ^ 1] + HW_OFF(j)) = __builtin_bit_cast(u16, (f16)hv);
    __syncthreads();                 // h[s+1] visible; prior-buffer reads all done
    xc = xn1; xn1 = xn2;
  }

  if (q == 0){                       // exact fp32 state out
    out[OUT_HT + b*HID + j] = hv;
    out[OUT_CT + b*HID + j] = cs;
    hf[j] = hv;
  }
  __syncthreads();

  if (t < 256){ // heads hidden, fp32: t<128 -> actor col t; else critic col t-128
    const float* W = (t < HID) ? Wa1 : Wc1;
    const int col  = t & (HID - 1);
    const f32x4* hp4 = (const f32x4*)hf;
    float a0 = 0.f, a1 = 0.f, a2 = 0.f, a3 = 0.f;
#pragma unroll
    for (int qq = 0; qq < 32; ++qq){
      f32x4 hh = hp4[qq];
      a0 = fmaf(hh.x, W[(u32)(4*qq+0)*HID + col], a0);
      a1 = fmaf(hh.y, W[(u32)(4*qq+1)*HID + col], a1);
      a2 = fmaf(hh.z, W[(u32)(4*qq+2)*HID + col], a2);
      a3 = fmaf(hh.w, W[(u32)(4*qq+3)*HID + col], a3);
    }
    float a = (a0 + a1) + (a2 + a3);
    hid[t] = (t < HID) ? tanhfast(a + ba1[col]) : tanhfast(a + bc1[col]);
  }
  __syncthreads();

  {
    const int wv = t >> 6, lane = t & 63;
    float p = 0.f;
    if (wv == 0)      p = hid[lane]     * Wa2[lane*2]   + hid[lane+64]     * Wa2[(lane+64)*2];
    else if (wv == 1) p = hid[lane]     * Wa2[lane*2+1] + hid[lane+64]     * Wa2[(lane+64)*2+1];
    else if (wv == 2) p = hid[128+lane] * Wc2[lane]     + hid[128+lane+64] * Wc2[lane+64];
#pragma unroll
    for (int off = 32; off > 0; off >>= 1) p += __shfl_down(p, off);
    if (lane == 0){
      if (wv == 0) out[b*2 + 0]   = p + ba2[0];
      if (wv == 1) out[b*2 + 1]   = p + ba2[1];
      if (wv == 2) out[OUT_VAL+b] = p + bc2[0];
    }
    if (b == 0 && wv == 3 && lane < 2) out[OUT_STD + lane] = expf(log_std[lane]);
  }
}

extern "C" void kernel_launch(void* const* d_in, const int* in_sizes, int n_in,
                              void* d_out, int out_size, void* d_ws, size_t ws_size,
                              hipStream_t stream)
{
  (void)in_sizes; (void)n_in; (void)out_size; (void)ws_size;
  const float* x    = (const float*)d_in[0];
  const float* h0   = (const float*)d_in[1];
  const float* c0   = (const float*)d_in[2];
  const float* Wx   = (const float*)d_in[3];
  const float* Wh   = (const float*)d_in[4];
  const float* bv   = (const float*)d_in[5];
  const float* Wa1  = (const float*)d_in[6];
  const float* ba1  = (const float*)d_in[7];
  const float* Wa2  = (const float*)d_in[8];
  const float* ba2  = (const float*)d_in[9];
  const float* lstd = (const float*)d_in[10];
  const float* Wc1  = (const float*)d_in[11];
  const float* bc1  = (const float*)d_in[12];
  const float* Wc2  = (const float*)d_in[13];
  const float* bc2  = (const float*)d_in[14];
  float* out = (float*)d_out;
  char*  ws  = (char*)d_ws;

  u16* xw  = (u16*)(ws + XW_OFF);
  u16* wxt = (u16*)(ws + WXT_OFF);

  k_pack_wxt<<<dim3(512),  dim3(256), 0, stream>>>(Wx, wxt);
  k_gemm<<<dim3(4096),     dim3(256), 0, stream>>>(x, wxt, xw);
  k_rnn<<<dim3(256),       dim3(512), 0, stream>>>(xw, Wh, h0, c0, bv,
                                                   Wa1, ba1, Wa2, ba2, Wc1, bc1, Wc2, bc2,
                                                   lstd, out);
}

// Round 18
// 824.187 us; speedup vs baseline: 1.0435x; 1.0292x over previous
//
#include <hip/hip_runtime.h>
#include <hip/hip_bf16.h>

typedef unsigned int   u32;
typedef unsigned short u16;
typedef _Float16       f16;
typedef __attribute__((ext_vector_type(2))) _Float16 f16x2;
typedef __attribute__((ext_vector_type(8))) _Float16 f16x8;
typedef __attribute__((ext_vector_type(4))) float    f32x4;
typedef __attribute__((ext_vector_type(4))) u32      u32x4;

#define T_STEPS 512
#define BATCH   256
#define O_IN    720
#define KPAD    736      // 720 padded to mult of 32 (zero pad in wxt)
#define HID     128
#define G4      512      // 4*HID
// d_out layout (floats): am[512] | std[2] | value[256] | hT[32768] | cT[32768]
#define OUT_STD 512
#define OUT_VAL 514
#define OUT_HT  770
#define OUT_CT  33538

// ws layout (bytes); requires ws_size >= ~135 MB
static const unsigned long long XW_OFF  = 0ull;          // f16 [131072][512] = 134217728 B
static const unsigned long long WXT_OFF = 134217728ull;  // f16 [512][736]    = 753664 B

// raw transcendental asm (R11-validated): v_exp_f32 = 2^x; v_rcp_f32 ~1ulp.
__device__ inline float exp2raw(float x){
  float r; asm("v_exp_f32 %0, %1" : "=v"(r) : "v"(x)); return r;
}
__device__ inline float rcpraw(float x){
  float r; asm("v_rcp_f32 %0, %1" : "=v"(r) : "v"(x)); return r;
}
__device__ inline float tanhfast(float x){
  return fmaf(2.f, rcpraw(1.0f + exp2raw(-2.88539008f * x)), -1.f);
}

// f16-pair dot2, inline asm (builtin broken: R2/R8; asm proven R9-R17).
__device__ inline float dot2f(u32 a, u32 b, float c){
  float d;
  asm("v_dot2_f32_f16 %0, %1, %2, %3" : "=v"(d) : "v"(a), "v"(b), "v"(c));
  return d;
}

// DPP quad_perm (VALU pipe; ctrls 177/78/0/85/170/255 HW-proven in R11-pass).
#define DPPF(x, ctrl) \
  __uint_as_float((u32)__builtin_amdgcn_update_dpp(0, (int)__float_as_uint(x), (ctrl), 0xF, 0xF, false))

// R11 h layout: f16, quarter q (32 halves = 64B) at byte q*80 (16B pad/quarter).
#define HQ_STRIDE 80
#define H_BYTES   (4*HQ_STRIDE)
#define HW_OFF(j) (((j)>>5)*HQ_STRIDE + ((j)&31)*2)

// ---------------- K0: Wx (720,512) f32 -> Wx^T f16 [512][736] zero-padded ----------------
__global__ void k_pack_wxt(const float* __restrict__ Wx, u16* __restrict__ wxt){
  const int n = blockIdx.x;               // 512 blocks
  for (int k = threadIdx.x; k < KPAD; k += 256){
    float v = (k < O_IN) ? Wx[(size_t)k * G4 + n] : 0.f;
    wxt[(size_t)n * KPAD + k] = __builtin_bit_cast(u16, (f16)v);
  }
}

// ---------------- K1 v4: xW = x @ Wx — 64x64 wave tile, 3 waves/SIMD ----------------------
// R17 (32x128, 3 waves): 385us — MFMA:B-load amortization halved vs 64x128 (2:1 vs 4:1).
// R18: 64x64 wave tile keeps 4:1 (16 MFMA : 4 B + 8 A loads/kc) AND fits 3 waves/SIMD:
// acc 64 + bF 16 + aF 16 + a0 32 + ptrs ~25 ≈ 160 <= 170 budget of waves_per_eu(3,3)
// (the attribute that fixed R16's spill). Block 256x64 (4 waves in M), grid 4096 = 8*512
// bijective XCD swizzle; 8 nb-siblings per mb co-resident -> x tile L2-reused 8x.
__global__ __attribute__((amdgpu_flat_work_group_size(256,256), amdgpu_waves_per_eu(3,3)))
void k_gemm(const float* __restrict__ x,
            const u16* __restrict__ wxt,
            u16* __restrict__ xw)
{
  const int l  = threadIdx.x & 63;
  const int w  = threadIdx.x >> 6;
  const int lr = l & 15;
  const int lk = l >> 4;
  const u32 L  = (blockIdx.x & 7u) * 512u + (blockIdx.x >> 3);
  const u32 mb = L >> 3, nb = L & 7u;
  const u32 M0 = mb * 256u + (u32)w * 64u;
  const u32 N0 = nb * 64u;

  const float* ax[4];
  const u16*   bx[4];
#pragma unroll
  for (int mf = 0; mf < 4; ++mf)
    ax[mf] = x + (unsigned long long)(M0 + mf*16 + lr) * O_IN + lk*8;
#pragma unroll
  for (int nf = 0; nf < 4; ++nf)
    bx[nf] = wxt + (unsigned long long)(N0 + nf*16 + lr) * KPAD + lk*8;

  f32x4 acc[4][4];
#pragma unroll
  for (int mf = 0; mf < 4; ++mf)
#pragma unroll
    for (int nf = 0; nf < 4; ++nf)
      acc[mf][nf] = (f32x4){0.f, 0.f, 0.f, 0.f};

  f32x4 a0[4][2];
  f16x8 aF[4], bF[4];

#pragma unroll
  for (int mf = 0; mf < 4; ++mf){
    a0[mf][0] = *(const f32x4*)(ax[mf]);
    a0[mf][1] = *(const f32x4*)(ax[mf] + 4);
  }
#pragma unroll
  for (int nf = 0; nf < 4; ++nf)
    bF[nf] = *(const f16x8*)(bx[nf]);
#pragma unroll
  for (int mf = 0; mf < 4; ++mf){
    f32x4 lo = a0[mf][0], hi = a0[mf][1];
    f16x8 v; v[0]=(f16)lo.x; v[1]=(f16)lo.y; v[2]=(f16)lo.z; v[3]=(f16)lo.w;
             v[4]=(f16)hi.x; v[5]=(f16)hi.y; v[6]=(f16)hi.z; v[7]=(f16)hi.w;
    aF[mf] = v;
  }

  for (int kc = 0; kc < 22; ++kc){
    if (kc < 21){                               // issue next A (long-latency) early
#pragma unroll
      for (int mf = 0; mf < 4; ++mf){
        a0[mf][0] = *(const f32x4*)(ax[mf] + (kc+1)*32);
        a0[mf][1] = *(const f32x4*)(ax[mf] + (kc+1)*32 + 4);
      }
    }
#pragma unroll
    for (int nf = 0; nf < 4; ++nf){
#pragma unroll
      for (int mf = 0; mf < 4; ++mf)
        acc[mf][nf] = __builtin_amdgcn_mfma_f32_16x16x32_f16(aF[mf], bF[nf], acc[mf][nf], 0, 0, 0);
      if (kc < 21)                              // reload B right after last use (L2-hit)
        bF[nf] = *(const f16x8*)(bx[nf] + (kc+1)*32);
    }
    if (kc < 21){
#pragma unroll
      for (int mf = 0; mf < 4; ++mf){
        f32x4 lo = a0[mf][0], hi = a0[mf][1];
        f16x8 v; v[0]=(f16)lo.x; v[1]=(f16)lo.y; v[2]=(f16)lo.z; v[3]=(f16)lo.w;
                 v[4]=(f16)hi.x; v[5]=(f16)hi.y; v[6]=(f16)hi.z; v[7]=(f16)hi.w;
        aF[mf] = v;
      }
    }
  }

  { // K tail: k = 704..719 valid (lanes lk<2), wxt zero-padded to 736
    f16x8 aT[4];
#pragma unroll
    for (int mf = 0; mf < 4; ++mf) aT[mf] = (f16x8)(f16)0.f;
    if (lk < 2){
#pragma unroll
      for (int mf = 0; mf < 4; ++mf){
        f32x4 lo = *(const f32x4*)(ax[mf] + 704);
        f32x4 hi = *(const f32x4*)(ax[mf] + 708);
        f16x8 v; v[0]=(f16)lo.x; v[1]=(f16)lo.y; v[2]=(f16)lo.z; v[3]=(f16)lo.w;
                 v[4]=(f16)hi.x; v[5]=(f16)hi.y; v[6]=(f16)hi.z; v[7]=(f16)hi.w;
        aT[mf] = v;
      }
    }
#pragma unroll
    for (int nf = 0; nf < 4; ++nf){
      f16x8 bT = *(const f16x8*)(bx[nf] + 704);
#pragma unroll
      for (int mf = 0; mf < 4; ++mf)
        acc[mf][nf] = __builtin_amdgcn_mfma_f32_16x16x32_f16(aT[mf], bT, acc[mf][nf], 0, 0, 0);
    }
  }

  // epilogue: D row = lk*4 + r, col = lr (proven mapping)
#pragma unroll
  for (int mf = 0; mf < 4; ++mf){
    const u32 rowb = M0 + mf*16 + lk*4;
#pragma unroll
    for (int nf = 0; nf < 4; ++nf){
      const u32 col = N0 + nf*16 + lr;
#pragma unroll
      for (int r = 0; r < 4; ++r)
        xw[(unsigned long long)(rowb + r) * G4 + col] = __builtin_bit_cast(u16, (f16)acc[mf][nf][r]);
    }
  }
}

// ---------------- K2: LSTM scan — VERBATIM R11 (proven: PASS 0.0078125, 459us) ------------
__global__ __attribute__((amdgpu_flat_work_group_size(512,512), amdgpu_waves_per_eu(2,2)))
void k_rnn(
    const u16* __restrict__ xw, const float* __restrict__ Wh,
    const float* __restrict__ h0, const float* __restrict__ c0,
    const float* __restrict__ bvec,
    const float* __restrict__ Wa1, const float* __restrict__ ba1,
    const float* __restrict__ Wa2, const float* __restrict__ ba2,
    const float* __restrict__ Wc1, const float* __restrict__ bc1,
    const float* __restrict__ Wc2, const float* __restrict__ bc2,
    const float* __restrict__ log_std, float* __restrict__ out)
{
  const int b = blockIdx.x;
  const int t = threadIdx.x;          // 0..511
  const int j = t >> 2;               // gate/h column 0..127
  const int q = t & 3;                // k-quarter & gate slot

  __shared__ __align__(16) char hbuf[2][H_BYTES];  // h f16, padded quarters, double-buffered
  __shared__ __align__(16) float hf[HID];          // final h fp32 (heads)
  __shared__ float hid[256];

  // ---- weights: wgN[m] = f16x2{ Wh[32q+2m][j+128N], Wh[32q+2m+1][j+128N] } ----
  u32 wg0[16], wg1[16], wg2[16], wg3[16];
#pragma unroll
  for (int m = 0; m < 16; ++m){
    const u32 kb = (u32)(32*q + 2*m) * G4 + (u32)j;
    f16x2 p;
    p[0]=(f16)Wh[kb      ]; p[1]=(f16)Wh[kb+G4      ]; wg0[m]=__builtin_bit_cast(u32,p);
    p[0]=(f16)Wh[kb+128  ]; p[1]=(f16)Wh[kb+G4+128  ]; wg1[m]=__builtin_bit_cast(u32,p);
    p[0]=(f16)Wh[kb+256  ]; p[1]=(f16)Wh[kb+G4+256  ]; wg2[m]=__builtin_bit_cast(u32,p);
    p[0]=(f16)Wh[kb+384  ]; p[1]=(f16)Wh[kb+G4+384  ]; wg3[m]=__builtin_bit_cast(u32,p);
  }
  // pin: opaque identity so the scheduler cannot sink the loads back into the loop
#pragma unroll
  for (int m = 0; m < 16; ++m){
    asm volatile("" : "+v"(wg0[m]));
    asm volatile("" : "+v"(wg1[m]));
    asm volatile("" : "+v"(wg2[m]));
    asm volatile("" : "+v"(wg3[m]));
  }
  const float bb = bvec[j + 128*q];   // bias for this thread's gate col

  // branchless activation constants: gate q==2 -> tanh(g)=2*sig(2g)-1, else sigmoid
  const float kexp  = (q == 2) ? -2.88539008f : -1.44269504f;
  const float postm = (q == 2) ? 2.f : 1.f;
  const float posta = (q == 2) ? -1.f : 0.f;

  // ---- state (replicated across the 4 partner lanes) ----
  float cs = c0[b*HID + j];
  float hv = h0[b*HID + j];
  if (q == 0)
    *(u16*)(hbuf[0] + HW_OFF(j)) = __builtin_bit_cast(u16, (f16)hv);
  __syncthreads();

  const u16* xp = xw + (u32)b * G4 + (u32)(j + 128*q);
  float xc  = (float)__builtin_bit_cast(f16, xp[0]) + bb;
  float xn1 = (T_STEPS > 1) ? (float)__builtin_bit_cast(f16, xp[131072u]) + bb : 0.f;

  for (int s = 0; s < T_STEPS; ++s){
    const char* hq = hbuf[s & 1] + q * HQ_STRIDE;

    float xn2 = 0.f;
    if (s + 2 < T_STEPS)
      xn2 = (float)__builtin_bit_cast(f16, xp[(u32)(s+2) * 131072u]) + bb;

    float p0 = 0.f, p1 = 0.f, p2 = 0.f, p3 = 0.f;
#pragma unroll
    for (int it = 0; it < 4; ++it){
      u32x4 hh = *(const u32x4*)(hq + it*16);    // 4 distinct addrs/wave, bank-disjoint
#pragma unroll
      for (int z = 0; z < 4; ++z){
        p0 = dot2f(hh[z], wg0[4*it+z], p0);
        p1 = dot2f(hh[z], wg1[4*it+z], p1);
        p2 = dot2f(hh[z], wg2[4*it+z], p2);
        p3 = dot2f(hh[z], wg3[4*it+z], p3);
      }
    }
    // reduce across the 4 partner lanes via DPP quad_perm (VALU, no DS traffic)
    p0 += DPPF(p0, 177);  p1 += DPPF(p1, 177);   // xor 1
    p2 += DPPF(p2, 177);  p3 += DPPF(p3, 177);
    p0 += DPPF(p0, 78);   p1 += DPPF(p1, 78);    // xor 2
    p2 += DPPF(p2, 78);   p3 += DPPF(p3, 78);

    // this lane activates gate q of col j: mul -> exp -> add -> rcp -> fma
    float gsum = (q == 0) ? p0 : (q == 1) ? p1 : (q == 2) ? p2 : p3;
    float gval = gsum + xc;
    float r    = rcpraw(1.0f + exp2raw(kexp * gval));
    float av   = fmaf(postm, r, posta);

    // gather the 4 activated gates from partner lanes (DPP quad broadcasts)
    float ai = DPPF(av, 0);     // lane lbase+0
    float af = DPPF(av, 85);    // lane lbase+1
    float ag = DPPF(av, 170);   // lane lbase+2
    float ao = DPPF(av, 255);   // lane lbase+3

    cs = af * cs + ai * ag;
    hv = ao * tanhfast(cs);
    if (q == 0)
      *(u16*)(hbuf[(s & 1) ^ 1] + HW_OFF(j)) = __builtin_bit_cast(u16, (f16)hv);
    __syncthreads();                 // h[s+1] visible; prior-buffer reads all done
    xc = xn1; xn1 = xn2;
  }

  if (q == 0){                       // exact fp32 state out
    out[OUT_HT + b*HID + j] = hv;
    out[OUT_CT + b*HID + j] = cs;
    hf[j] = hv;
  }
  __syncthreads();

  if (t < 256){ // heads hidden, fp32: t<128 -> actor col t; else critic col t-128
    const float* W = (t < HID) ? Wa1 : Wc1;
    const int col  = t & (HID - 1);
    const f32x4* hp4 = (const f32x4*)hf;
    float a0 = 0.f, a1 = 0.f, a2 = 0.f, a3 = 0.f;
#pragma unroll
    for (int qq = 0; qq < 32; ++qq){
      f32x4 hh = hp4[qq];
      a0 = fmaf(hh.x, W[(u32)(4*qq+0)*HID + col], a0);
      a1 = fmaf(hh.y, W[(u32)(4*qq+1)*HID + col], a1);
      a2 = fmaf(hh.z, W[(u32)(4*qq+2)*HID + col], a2);
      a3 = fmaf(hh.w, W[(u32)(4*qq+3)*HID + col], a3);
    }
    float a = (a0 + a1) + (a2 + a3);
    hid[t] = (t < HID) ? tanhfast(a + ba1[col]) : tanhfast(a + bc1[col]);
  }
  __syncthreads();

  {
    const int wv = t >> 6, lane = t & 63;
    float p = 0.f;
    if (wv == 0)      p = hid[lane]     * Wa2[lane*2]   + hid[lane+64]     * Wa2[(lane+64)*2];
    else if (wv == 1) p = hid[lane]     * Wa2[lane*2+1] + hid[lane+64]     * Wa2[(lane+64)*2+1];
    else if (wv == 2) p = hid[128+lane] * Wc2[lane]     + hid[128+lane+64] * Wc2[lane+64];
#pragma unroll
    for (int off = 32; off > 0; off >>= 1) p += __shfl_down(p, off);
    if (lane == 0){
      if (wv == 0) out[b*2 + 0]   = p + ba2[0];
      if (wv == 1) out[b*2 + 1]   = p + ba2[1];
      if (wv == 2) out[OUT_VAL+b] = p + bc2[0];
    }
    if (b == 0 && wv == 3 && lane < 2) out[OUT_STD + lane] = expf(log_std[lane]);
  }
}

extern "C" void kernel_launch(void* const* d_in, const int* in_sizes, int n_in,
                              void* d_out, int out_size, void* d_ws, size_t ws_size,
                              hipStream_t stream)
{
  (void)in_sizes; (void)n_in; (void)out_size; (void)ws_size;
  const float* x    = (const float*)d_in[0];
  const float* h0   = (const float*)d_in[1];
  const float* c0   = (const float*)d_in[2];
  const float* Wx   = (const float*)d_in[3];
  const float* Wh   = (const float*)d_in[4];
  const float* bv   = (const float*)d_in[5];
  const float* Wa1  = (const float*)d_in[6];
  const float* ba1  = (const float*)d_in[7];
  const float* Wa2  = (const float*)d_in[8];
  const float* ba2  = (const float*)d_in[9];
  const float* lstd = (const float*)d_in[10];
  const float* Wc1  = (const float*)d_in[11];
  const float* bc1  = (const float*)d_in[12];
  const float* Wc2  = (const float*)d_in[13];
  const float* bc2  = (const float*)d_in[14];
  float* out = (float*)d_out;
  char*  ws  = (char*)d_ws;

  u16* xw  = (u16*)(ws + XW_OFF);
  u16* wxt = (u16*)(ws + WXT_OFF);

  k_pack_wxt<<<dim3(512),  dim3(256), 0, stream>>>(Wx, wxt);
  k_gemm<<<dim3(4096),     dim3(256), 0, stream>>>(x, wxt, xw);
  k_rnn<<<dim3(256),       dim3(512), 0, stream>>>(xw, Wh, h0, c0, bv,
                                                   Wa1, ba1, Wa2, ba2, Wc1, bc1, Wc2, bc2,
                                                   lstd, out);
}

// Round 19
// 721.198 us; speedup vs baseline: 1.1925x; 1.1428x over previous
//
#include <hip/hip_runtime.h>
#include <hip/hip_bf16.h>

typedef unsigned int   u32;
typedef unsigned short u16;
typedef _Float16       f16;
typedef __attribute__((ext_vector_type(2))) _Float16 f16x2;
typedef __attribute__((ext_vector_type(8))) _Float16 f16x8;
typedef __attribute__((ext_vector_type(4))) float    f32x4;
typedef __attribute__((ext_vector_type(4))) u32      u32x4;

#define T_STEPS 512
#define BATCH   256
#define O_IN    720
#define KPAD    736      // 720 padded to mult of 32 (zero pad in wxt)
#define HID     128
#define G4      512      // 4*HID
// d_out layout (floats): am[512] | std[2] | value[256] | hT[32768] | cT[32768]
#define OUT_STD 512
#define OUT_VAL 514
#define OUT_HT  770
#define OUT_CT  33538

// ws layout (bytes); requires ws_size >= ~135 MB
static const unsigned long long XW_OFF  = 0ull;          // f16 [131072][512] = 134217728 B
static const unsigned long long WXT_OFF = 134217728ull;  // f16 [512][736]    = 753664 B

// raw transcendental asm (R11-validated): v_exp_f32 = 2^x; v_rcp_f32 ~1ulp.
__device__ inline float exp2raw(float x){
  float r; asm("v_exp_f32 %0, %1" : "=v"(r) : "v"(x)); return r;
}
__device__ inline float rcpraw(float x){
  float r; asm("v_rcp_f32 %0, %1" : "=v"(r) : "v"(x)); return r;
}
__device__ inline float tanhfast(float x){
  return fmaf(2.f, rcpraw(1.0f + exp2raw(-2.88539008f * x)), -1.f);
}

// f16-pair dot2, inline asm (builtin broken: R2/R8; asm proven R9-R18).
__device__ inline float dot2f(u32 a, u32 b, float c){
  float d;
  asm("v_dot2_f32_f16 %0, %1, %2, %3" : "=v"(d) : "v"(a), "v"(b), "v"(c));
  return d;
}

// DPP quad_perm (VALU pipe; ctrls 177/78/0/85/170/255 HW-proven in R11-pass).
#define DPPF(x, ctrl) \
  __uint_as_float((u32)__builtin_amdgcn_update_dpp(0, (int)__float_as_uint(x), (ctrl), 0xF, 0xF, false))

// R11 h layout: f16, quarter q (32 halves = 64B) at byte q*80 (16B pad/quarter).
#define HQ_STRIDE 80
#define H_BYTES   (4*HQ_STRIDE)
#define HW_OFF(j) (((j)>>5)*HQ_STRIDE + ((j)&31)*2)

// ---------------- K0: Wx (720,512) f32 -> Wx^T f16 [512][736] zero-padded ----------------
__global__ void k_pack_wxt(const float* __restrict__ Wx, u16* __restrict__ wxt){
  const int n = blockIdx.x;               // 512 blocks
  for (int k = threadIdx.x; k < KPAD; k += 256){
    float v = (k < O_IN) ? Wx[(size_t)k * G4 + n] : 0.f;
    wxt[(size_t)n * KPAD + k] = __builtin_bit_cast(u16, (f16)v);
  }
}

// ---------------- K1: xW = x @ Wx — VERBATIM R3/R11 64x128-wave kernel (proven ~260us) ----
// Tile scorecard: 32x128+spill 463 / 32x128 385 / 64x64 360 / THIS 260. For the LDS-free
// design, per-wave MFMA:load amortization (32:16) beats +1 wave/SIMD occupancy.
__global__ __launch_bounds__(256, 2) void k_gemm(const float* __restrict__ x,
                                                 const u16* __restrict__ wxt,
                                                 u16* __restrict__ xw)
{
  const int l  = threadIdx.x & 63;
  const int w  = threadIdx.x >> 6;
  const int lr = l & 15;
  const int lk = l >> 4;
  const u32 L  = (blockIdx.x & 7u) * 256u + (blockIdx.x >> 3);
  const u32 mb = L >> 2, nb = L & 3u;
  const u32 M0 = mb * 256u + (u32)w * 64u;
  const u32 N0 = nb * 128u;

  const float* ax[4];
  const u16*   bx[8];
#pragma unroll
  for (int mf = 0; mf < 4; ++mf)
    ax[mf] = x + (unsigned long long)(M0 + mf*16 + lr) * O_IN + lk*8;
#pragma unroll
  for (int nf = 0; nf < 8; ++nf)
    bx[nf] = wxt + (unsigned long long)(N0 + nf*16 + lr) * KPAD + lk*8;

  f32x4 acc[4][8];
#pragma unroll
  for (int mf = 0; mf < 4; ++mf)
#pragma unroll
    for (int nf = 0; nf < 8; ++nf)
      acc[mf][nf] = (f32x4){0.f, 0.f, 0.f, 0.f};

  f32x4 a0[4][2];
  f16x8 aF[4], bF[8];

#pragma unroll
  for (int mf = 0; mf < 4; ++mf){
    a0[mf][0] = *(const f32x4*)(ax[mf]);
    a0[mf][1] = *(const f32x4*)(ax[mf] + 4);
  }
#pragma unroll
  for (int nf = 0; nf < 8; ++nf)
    bF[nf] = *(const f16x8*)(bx[nf]);
#pragma unroll
  for (int mf = 0; mf < 4; ++mf){
    f32x4 lo = a0[mf][0], hi = a0[mf][1];
    f16x8 v; v[0]=(f16)lo.x; v[1]=(f16)lo.y; v[2]=(f16)lo.z; v[3]=(f16)lo.w;
             v[4]=(f16)hi.x; v[5]=(f16)hi.y; v[6]=(f16)hi.z; v[7]=(f16)hi.w;
    aF[mf] = v;
  }

  for (int kc = 0; kc < 22; ++kc){
    if (kc < 21){                               // issue next A (long-latency) early
#pragma unroll
      for (int mf = 0; mf < 4; ++mf){
        a0[mf][0] = *(const f32x4*)(ax[mf] + (kc+1)*32);
        a0[mf][1] = *(const f32x4*)(ax[mf] + (kc+1)*32 + 4);
      }
    }
#pragma unroll
    for (int nf = 0; nf < 8; ++nf){
#pragma unroll
      for (int mf = 0; mf < 4; ++mf)
        acc[mf][nf] = __builtin_amdgcn_mfma_f32_16x16x32_f16(aF[mf], bF[nf], acc[mf][nf], 0, 0, 0);
      if (kc < 21)                              // reload B right after last use (L2-hit)
        bF[nf] = *(const f16x8*)(bx[nf] + (kc+1)*32);
    }
    if (kc < 21){
#pragma unroll
      for (int mf = 0; mf < 4; ++mf){
        f32x4 lo = a0[mf][0], hi = a0[mf][1];
        f16x8 v; v[0]=(f16)lo.x; v[1]=(f16)lo.y; v[2]=(f16)lo.z; v[3]=(f16)lo.w;
                 v[4]=(f16)hi.x; v[5]=(f16)hi.y; v[6]=(f16)hi.z; v[7]=(f16)hi.w;
        aF[mf] = v;
      }
    }
  }

  { // K tail: k = 704..719 valid (lanes lk<2), wxt zero-padded to 736
    f16x8 aT[4];
#pragma unroll
    for (int mf = 0; mf < 4; ++mf) aT[mf] = (f16x8)(f16)0.f;
    if (lk < 2){
#pragma unroll
      for (int mf = 0; mf < 4; ++mf){
        f32x4 lo = *(const f32x4*)(ax[mf] + 704);
        f32x4 hi = *(const f32x4*)(ax[mf] + 708);
        f16x8 v; v[0]=(f16)lo.x; v[1]=(f16)lo.y; v[2]=(f16)lo.z; v[3]=(f16)lo.w;
                 v[4]=(f16)hi.x; v[5]=(f16)hi.y; v[6]=(f16)hi.z; v[7]=(f16)hi.w;
        aT[mf] = v;
      }
    }
#pragma unroll
    for (int nf = 0; nf < 8; ++nf){
      f16x8 bT = *(const f16x8*)(bx[nf] + 704);
#pragma unroll
      for (int mf = 0; mf < 4; ++mf)
        acc[mf][nf] = __builtin_amdgcn_mfma_f32_16x16x32_f16(aT[mf], bT, acc[mf][nf], 0, 0, 0);
    }
  }

  // epilogue: D row = lk*4 + r, col = lr (proven mapping)
#pragma unroll
  for (int mf = 0; mf < 4; ++mf){
    const u32 rowb = M0 + mf*16 + lk*4;
#pragma unroll
    for (int nf = 0; nf < 8; ++nf){
      const u32 col = N0 + nf*16 + lr;
#pragma unroll
      for (int r = 0; r < 4; ++r)
        xw[(unsigned long long)(rowb + r) * G4 + col] = __builtin_bit_cast(u16, (f16)acc[mf][nf][r]);
    }
  }
}

// ---------------- K2: LSTM scan — VERBATIM R11 (proven: PASS 0.0078125, 459us) ------------
__global__ __attribute__((amdgpu_flat_work_group_size(512,512), amdgpu_waves_per_eu(2,2)))
void k_rnn(
    const u16* __restrict__ xw, const float* __restrict__ Wh,
    const float* __restrict__ h0, const float* __restrict__ c0,
    const float* __restrict__ bvec,
    const float* __restrict__ Wa1, const float* __restrict__ ba1,
    const float* __restrict__ Wa2, const float* __restrict__ ba2,
    const float* __restrict__ Wc1, const float* __restrict__ bc1,
    const float* __restrict__ Wc2, const float* __restrict__ bc2,
    const float* __restrict__ log_std, float* __restrict__ out)
{
  const int b = blockIdx.x;
  const int t = threadIdx.x;          // 0..511
  const int j = t >> 2;               // gate/h column 0..127
  const int q = t & 3;                // k-quarter & gate slot

  __shared__ __align__(16) char hbuf[2][H_BYTES];  // h f16, padded quarters, double-buffered
  __shared__ __align__(16) float hf[HID];          // final h fp32 (heads)
  __shared__ float hid[256];

  // ---- weights: wgN[m] = f16x2{ Wh[32q+2m][j+128N], Wh[32q+2m+1][j+128N] } ----
  u32 wg0[16], wg1[16], wg2[16], wg3[16];
#pragma unroll
  for (int m = 0; m < 16; ++m){
    const u32 kb = (u32)(32*q + 2*m) * G4 + (u32)j;
    f16x2 p;
    p[0]=(f16)Wh[kb      ]; p[1]=(f16)Wh[kb+G4      ]; wg0[m]=__builtin_bit_cast(u32,p);
    p[0]=(f16)Wh[kb+128  ]; p[1]=(f16)Wh[kb+G4+128  ]; wg1[m]=__builtin_bit_cast(u32,p);
    p[0]=(f16)Wh[kb+256  ]; p[1]=(f16)Wh[kb+G4+256  ]; wg2[m]=__builtin_bit_cast(u32,p);
    p[0]=(f16)Wh[kb+384  ]; p[1]=(f16)Wh[kb+G4+384  ]; wg3[m]=__builtin_bit_cast(u32,p);
  }
  // pin: opaque identity so the scheduler cannot sink the loads back into the loop
#pragma unroll
  for (int m = 0; m < 16; ++m){
    asm volatile("" : "+v"(wg0[m]));
    asm volatile("" : "+v"(wg1[m]));
    asm volatile("" : "+v"(wg2[m]));
    asm volatile("" : "+v"(wg3[m]));
  }
  const float bb = bvec[j + 128*q];   // bias for this thread's gate col

  // branchless activation constants: gate q==2 -> tanh(g)=2*sig(2g)-1, else sigmoid
  const float kexp  = (q == 2) ? -2.88539008f : -1.44269504f;
  const float postm = (q == 2) ? 2.f : 1.f;
  const float posta = (q == 2) ? -1.f : 0.f;

  // ---- state (replicated across the 4 partner lanes) ----
  float cs = c0[b*HID + j];
  float hv = h0[b*HID + j];
  if (q == 0)
    *(u16*)(hbuf[0] + HW_OFF(j)) = __builtin_bit_cast(u16, (f16)hv);
  __syncthreads();

  const u16* xp = xw + (u32)b * G4 + (u32)(j + 128*q);
  float xc  = (float)__builtin_bit_cast(f16, xp[0]) + bb;
  float xn1 = (T_STEPS > 1) ? (float)__builtin_bit_cast(f16, xp[131072u]) + bb : 0.f;

  for (int s = 0; s < T_STEPS; ++s){
    const char* hq = hbuf[s & 1] + q * HQ_STRIDE;

    float xn2 = 0.f;
    if (s + 2 < T_STEPS)
      xn2 = (float)__builtin_bit_cast(f16, xp[(u32)(s+2) * 131072u]) + bb;

    float p0 = 0.f, p1 = 0.f, p2 = 0.f, p3 = 0.f;
#pragma unroll
    for (int it = 0; it < 4; ++it){
      u32x4 hh = *(const u32x4*)(hq + it*16);    // 4 distinct addrs/wave, bank-disjoint
#pragma unroll
      for (int z = 0; z < 4; ++z){
        p0 = dot2f(hh[z], wg0[4*it+z], p0);
        p1 = dot2f(hh[z], wg1[4*it+z], p1);
        p2 = dot2f(hh[z], wg2[4*it+z], p2);
        p3 = dot2f(hh[z], wg3[4*it+z], p3);
      }
    }
    // reduce across the 4 partner lanes via DPP quad_perm (VALU, no DS traffic)
    p0 += DPPF(p0, 177);  p1 += DPPF(p1, 177);   // xor 1
    p2 += DPPF(p2, 177);  p3 += DPPF(p3, 177);
    p0 += DPPF(p0, 78);   p1 += DPPF(p1, 78);    // xor 2
    p2 += DPPF(p2, 78);   p3 += DPPF(p3, 78);

    // this lane activates gate q of col j: mul -> exp -> add -> rcp -> fma
    float gsum = (q == 0) ? p0 : (q == 1) ? p1 : (q == 2) ? p2 : p3;
    float gval = gsum + xc;
    float r    = rcpraw(1.0f + exp2raw(kexp * gval));
    float av   = fmaf(postm, r, posta);

    // gather the 4 activated gates from partner lanes (DPP quad broadcasts)
    float ai = DPPF(av, 0);     // lane lbase+0
    float af = DPPF(av, 85);    // lane lbase+1
    float ag = DPPF(av, 170);   // lane lbase+2
    float ao = DPPF(av, 255);   // lane lbase+3

    cs = af * cs + ai * ag;
    hv = ao * tanhfast(cs);
    if (q == 0)
      *(u16*)(hbuf[(s & 1) ^ 1] + HW_OFF(j)) = __builtin_bit_cast(u16, (f16)hv);
    __syncthreads();                 // h[s+1] visible; prior-buffer reads all done
    xc = xn1; xn1 = xn2;
  }

  if (q == 0){                       // exact fp32 state out
    out[OUT_HT + b*HID + j] = hv;
    out[OUT_CT + b*HID + j] = cs;
    hf[j] = hv;
  }
  __syncthreads();

  if (t < 256){ // heads hidden, fp32: t<128 -> actor col t; else critic col t-128
    const float* W = (t < HID) ? Wa1 : Wc1;
    const int col  = t & (HID - 1);
    const f32x4* hp4 = (const f32x4*)hf;
    float a0 = 0.f, a1 = 0.f, a2 = 0.f, a3 = 0.f;
#pragma unroll
    for (int qq = 0; qq < 32; ++qq){
      f32x4 hh = hp4[qq];
      a0 = fmaf(hh.x, W[(u32)(4*qq+0)*HID + col], a0);
      a1 = fmaf(hh.y, W[(u32)(4*qq+1)*HID + col], a1);
      a2 = fmaf(hh.z, W[(u32)(4*qq+2)*HID + col], a2);
      a3 = fmaf(hh.w, W[(u32)(4*qq+3)*HID + col], a3);
    }
    float a = (a0 + a1) + (a2 + a3);
    hid[t] = (t < HID) ? tanhfast(a + ba1[col]) : tanhfast(a + bc1[col]);
  }
  __syncthreads();

  {
    const int wv = t >> 6, lane = t & 63;
    float p = 0.f;
    if (wv == 0)      p = hid[lane]     * Wa2[lane*2]   + hid[lane+64]     * Wa2[(lane+64)*2];
    else if (wv == 1) p = hid[lane]     * Wa2[lane*2+1] + hid[lane+64]     * Wa2[(lane+64)*2+1];
    else if (wv == 2) p = hid[128+lane] * Wc2[lane]     + hid[128+lane+64] * Wc2[lane+64];
#pragma unroll
    for (int off = 32; off > 0; off >>= 1) p += __shfl_down(p, off);
    if (lane == 0){
      if (wv == 0) out[b*2 + 0]   = p + ba2[0];
      if (wv == 1) out[b*2 + 1]   = p + ba2[1];
      if (wv == 2) out[OUT_VAL+b] = p + bc2[0];
    }
    if (b == 0 && wv == 3 && lane < 2) out[OUT_STD + lane] = expf(log_std[lane]);
  }
}

extern "C" void kernel_launch(void* const* d_in, const int* in_sizes, int n_in,
                              void* d_out, int out_size, void* d_ws, size_t ws_size,
                              hipStream_t stream)
{
  (void)in_sizes; (void)n_in; (void)out_size; (void)ws_size;
  const float* x    = (const float*)d_in[0];
  const float* h0   = (const float*)d_in[1];
  const float* c0   = (const float*)d_in[2];
  const float* Wx   = (const float*)d_in[3];
  const float* Wh   = (const float*)d_in[4];
  const float* bv   = (const float*)d_in[5];
  const float* Wa1  = (const float*)d_in[6];
  const float* ba1  = (const float*)d_in[7];
  const float* Wa2  = (const float*)d_in[8];
  const float* ba2  = (const float*)d_in[9];
  const float* lstd = (const float*)d_in[10];
  const float* Wc1  = (const float*)d_in[11];
  const float* bc1  = (const float*)d_in[12];
  const float* Wc2  = (const float*)d_in[13];
  const float* bc2  = (const float*)d_in[14];
  float* out = (float*)d_out;
  char*  ws  = (char*)d_ws;

  u16* xw  = (u16*)(ws + XW_OFF);
  u16* wxt = (u16*)(ws + WXT_OFF);

  k_pack_wxt<<<dim3(512),  dim3(256), 0, stream>>>(Wx, wxt);
  k_gemm<<<dim3(2048),     dim3(256), 0, stream>>>(x, wxt, xw);
  k_rnn<<<dim3(256),       dim3(512), 0, stream>>>(xw, Wh, h0, c0, bv,
                                                   Wa1, ba1, Wa2, ba2, Wc1, bc1, Wc2, bc2,
                                                   lstd, out);
}

// Round 21
// 721.066 us; speedup vs baseline: 1.1927x; 1.0002x over previous
//
#include <hip/hip_runtime.h>
#include <hip/hip_bf16.h>

typedef unsigned int   u32;
typedef unsigned short u16;
typedef _Float16       f16;
typedef __attribute__((ext_vector_type(2))) _Float16 f16x2;
typedef __attribute__((ext_vector_type(8))) _Float16 f16x8;
typedef __attribute__((ext_vector_type(4))) float    f32x4;
typedef __attribute__((ext_vector_type(4))) u32      u32x4;

#define T_STEPS 512
#define BATCH   256
#define O_IN    720
#define KPAD    736      // 720 padded to mult of 32 (zero pad in wxt)
#define HID     128
#define G4      512      // 4*HID
// d_out layout (floats): am[512] | std[2] | value[256] | hT[32768] | cT[32768]
#define OUT_STD 512
#define OUT_VAL 514
#define OUT_HT  770
#define OUT_CT  33538

// ws layout (bytes); requires ws_size >= ~135 MB
static const unsigned long long XW_OFF  = 0ull;          // f16 [131072][512] = 134217728 B
static const unsigned long long WXT_OFF = 134217728ull;  // f16 [512][736]    = 753664 B

// raw transcendental asm (R11-validated): v_exp_f32 = 2^x; v_rcp_f32 ~1ulp.
__device__ inline float exp2raw(float x){
  float r; asm("v_exp_f32 %0, %1" : "=v"(r) : "v"(x)); return r;
}
__device__ inline float rcpraw(float x){
  float r; asm("v_rcp_f32 %0, %1" : "=v"(r) : "v"(x)); return r;
}
__device__ inline float tanhfast(float x){
  return fmaf(2.f, rcpraw(1.0f + exp2raw(-2.88539008f * x)), -1.f);
}

// f16-pair dot2, inline asm (builtin broken: R2/R8; asm proven R9-R19).
__device__ inline float dot2f(u32 a, u32 b, float c){
  float d;
  asm("v_dot2_f32_f16 %0, %1, %2, %3" : "=v"(d) : "v"(a), "v"(b), "v"(c));
  return d;
}

// DPP quad_perm (VALU pipe; ctrls 177/78/0/85/170/255 HW-proven in R11-pass).
#define DPPF(x, ctrl) \
  __uint_as_float((u32)__builtin_amdgcn_update_dpp(0, (int)__float_as_uint(x), (ctrl), 0xF, 0xF, false))

// R11 h layout: f16, quarter q (32 halves = 64B) at byte q*80 (16B pad/quarter).
#define HQ_STRIDE 80
#define H_BYTES   (4*HQ_STRIDE)
#define HW_OFF(j) (((j)>>5)*HQ_STRIDE + ((j)&31)*2)

// ---------------- K0: Wx (720,512) f32 -> Wx^T f16 [512][736] zero-padded ----------------
__global__ void k_pack_wxt(const float* __restrict__ Wx, u16* __restrict__ wxt){
  const int n = blockIdx.x;               // 512 blocks
  for (int k = threadIdx.x; k < KPAD; k += 256){
    float v = (k < O_IN) ? Wx[(size_t)k * G4 + n] : 0.f;
    wxt[(size_t)n * KPAD + k] = __builtin_bit_cast(u16, (f16)v);
  }
}

// ---------------- K1: xW = x @ Wx — VERBATIM R3/R11 64x128-wave kernel (proven ~260us) ----
// Tile scorecard: 32x128+spill 463 / 32x128 385 / 64x64 360 / THIS 260. For the LDS-free
// design, per-wave MFMA:load amortization (32:16) beats +1 wave/SIMD occupancy.
__global__ __launch_bounds__(256, 2) void k_gemm(const float* __restrict__ x,
                                                 const u16* __restrict__ wxt,
                                                 u16* __restrict__ xw)
{
  const int l  = threadIdx.x & 63;
  const int w  = threadIdx.x >> 6;
  const int lr = l & 15;
  const int lk = l >> 4;
  const u32 L  = (blockIdx.x & 7u) * 256u + (blockIdx.x >> 3);
  const u32 mb = L >> 2, nb = L & 3u;
  const u32 M0 = mb * 256u + (u32)w * 64u;
  const u32 N0 = nb * 128u;

  const float* ax[4];
  const u16*   bx[8];
#pragma unroll
  for (int mf = 0; mf < 4; ++mf)
    ax[mf] = x + (unsigned long long)(M0 + mf*16 + lr) * O_IN + lk*8;
#pragma unroll
  for (int nf = 0; nf < 8; ++nf)
    bx[nf] = wxt + (unsigned long long)(N0 + nf*16 + lr) * KPAD + lk*8;

  f32x4 acc[4][8];
#pragma unroll
  for (int mf = 0; mf < 4; ++mf)
#pragma unroll
    for (int nf = 0; nf < 8; ++nf)
      acc[mf][nf] = (f32x4){0.f, 0.f, 0.f, 0.f};

  f32x4 a0[4][2];
  f16x8 aF[4], bF[8];

#pragma unroll
  for (int mf = 0; mf < 4; ++mf){
    a0[mf][0] = *(const f32x4*)(ax[mf]);
    a0[mf][1] = *(const f32x4*)(ax[mf] + 4);
  }
#pragma unroll
  for (int nf = 0; nf < 8; ++nf)
    bF[nf] = *(const f16x8*)(bx[nf]);
#pragma unroll
  for (int mf = 0; mf < 4; ++mf){
    f32x4 lo = a0[mf][0], hi = a0[mf][1];
    f16x8 v; v[0]=(f16)lo.x; v[1]=(f16)lo.y; v[2]=(f16)lo.z; v[3]=(f16)lo.w;
             v[4]=(f16)hi.x; v[5]=(f16)hi.y; v[6]=(f16)hi.z; v[7]=(f16)hi.w;
    aF[mf] = v;
  }

  for (int kc = 0; kc < 22; ++kc){
    if (kc < 21){                               // issue next A (long-latency) early
#pragma unroll
      for (int mf = 0; mf < 4; ++mf){
        a0[mf][0] = *(const f32x4*)(ax[mf] + (kc+1)*32);
        a0[mf][1] = *(const f32x4*)(ax[mf] + (kc+1)*32 + 4);
      }
    }
#pragma unroll
    for (int nf = 0; nf < 8; ++nf){
#pragma unroll
      for (int mf = 0; mf < 4; ++mf)
        acc[mf][nf] = __builtin_amdgcn_mfma_f32_16x16x32_f16(aF[mf], bF[nf], acc[mf][nf], 0, 0, 0);
      if (kc < 21)                              // reload B right after last use (L2-hit)
        bF[nf] = *(const f16x8*)(bx[nf] + (kc+1)*32);
    }
    if (kc < 21){
#pragma unroll
      for (int mf = 0; mf < 4; ++mf){
        f32x4 lo = a0[mf][0], hi = a0[mf][1];
        f16x8 v; v[0]=(f16)lo.x; v[1]=(f16)lo.y; v[2]=(f16)lo.z; v[3]=(f16)lo.w;
                 v[4]=(f16)hi.x; v[5]=(f16)hi.y; v[6]=(f16)hi.z; v[7]=(f16)hi.w;
        aF[mf] = v;
      }
    }
  }

  { // K tail: k = 704..719 valid (lanes lk<2), wxt zero-padded to 736
    f16x8 aT[4];
#pragma unroll
    for (int mf = 0; mf < 4; ++mf) aT[mf] = (f16x8)(f16)0.f;
    if (lk < 2){
#pragma unroll
      for (int mf = 0; mf < 4; ++mf){
        f32x4 lo = *(const f32x4*)(ax[mf] + 704);
        f32x4 hi = *(const f32x4*)(ax[mf] + 708);
        f16x8 v; v[0]=(f16)lo.x; v[1]=(f16)lo.y; v[2]=(f16)lo.z; v[3]=(f16)lo.w;
                 v[4]=(f16)hi.x; v[5]=(f16)hi.y; v[6]=(f16)hi.z; v[7]=(f16)hi.w;
        aT[mf] = v;
      }
    }
#pragma unroll
    for (int nf = 0; nf < 8; ++nf){
      f16x8 bT = *(const f16x8*)(bx[nf] + 704);
#pragma unroll
      for (int mf = 0; mf < 4; ++mf)
        acc[mf][nf] = __builtin_amdgcn_mfma_f32_16x16x32_f16(aT[mf], bT, acc[mf][nf], 0, 0, 0);
    }
  }

  // epilogue: D row = lk*4 + r, col = lr (proven mapping)
#pragma unroll
  for (int mf = 0; mf < 4; ++mf){
    const u32 rowb = M0 + mf*16 + lk*4;
#pragma unroll
    for (int nf = 0; nf < 8; ++nf){
      const u32 col = N0 + nf*16 + lr;
#pragma unroll
      for (int r = 0; r < 4; ++r)
        xw[(unsigned long long)(rowb + r) * G4 + col] = __builtin_bit_cast(u16, (f16)acc[mf][nf][r]);
    }
  }
}

// ---------------- K2: LSTM scan — VERBATIM R11 (proven: PASS 0.0078125, ~455us) -----------
__global__ __attribute__((amdgpu_flat_work_group_size(512,512), amdgpu_waves_per_eu(2,2)))
void k_rnn(
    const u16* __restrict__ xw, const float* __restrict__ Wh,
    const float* __restrict__ h0, const float* __restrict__ c0,
    const float* __restrict__ bvec,
    const float* __restrict__ Wa1, const float* __restrict__ ba1,
    const float* __restrict__ Wa2, const float* __restrict__ ba2,
    const float* __restrict__ Wc1, const float* __restrict__ bc1,
    const float* __restrict__ Wc2, const float* __restrict__ bc2,
    const float* __restrict__ log_std, float* __restrict__ out)
{
  const int b = blockIdx.x;
  const int t = threadIdx.x;          // 0..511
  const int j = t >> 2;               // gate/h column 0..127
  const int q = t & 3;                // k-quarter & gate slot

  __shared__ __align__(16) char hbuf[2][H_BYTES];  // h f16, padded quarters, double-buffered
  __shared__ __align__(16) float hf[HID];          // final h fp32 (heads)
  __shared__ float hid[256];

  // ---- weights: wgN[m] = f16x2{ Wh[32q+2m][j+128N], Wh[32q+2m+1][j+128N] } ----
  u32 wg0[16], wg1[16], wg2[16], wg3[16];
#pragma unroll
  for (int m = 0; m < 16; ++m){
    const u32 kb = (u32)(32*q + 2*m) * G4 + (u32)j;
    f16x2 p;
    p[0]=(f16)Wh[kb      ]; p[1]=(f16)Wh[kb+G4      ]; wg0[m]=__builtin_bit_cast(u32,p);
    p[0]=(f16)Wh[kb+128  ]; p[1]=(f16)Wh[kb+G4+128  ]; wg1[m]=__builtin_bit_cast(u32,p);
    p[0]=(f16)Wh[kb+256  ]; p[1]=(f16)Wh[kb+G4+256  ]; wg2[m]=__builtin_bit_cast(u32,p);
    p[0]=(f16)Wh[kb+384  ]; p[1]=(f16)Wh[kb+G4+384  ]; wg3[m]=__builtin_bit_cast(u32,p);
  }
  // pin: opaque identity so the scheduler cannot sink the loads back into the loop
#pragma unroll
  for (int m = 0; m < 16; ++m){
    asm volatile("" : "+v"(wg0[m]));
    asm volatile("" : "+v"(wg1[m]));
    asm volatile("" : "+v"(wg2[m]));
    asm volatile("" : "+v"(wg3[m]));
  }
  const float bb = bvec[j + 128*q];   // bias for this thread's gate col

  // branchless activation constants: gate q==2 -> tanh(g)=2*sig(2g)-1, else sigmoid
  const float kexp  = (q == 2) ? -2.88539008f : -1.44269504f;
  const float postm = (q == 2) ? 2.f : 1.f;
  const float posta = (q == 2) ? -1.f : 0.f;

  // ---- state (replicated across the 4 partner lanes) ----
  float cs = c0[b*HID + j];
  float hv = h0[b*HID + j];
  if (q == 0)
    *(u16*)(hbuf[0] + HW_OFF(j)) = __builtin_bit_cast(u16, (f16)hv);
  __syncthreads();

  const u16* xp = xw + (u32)b * G4 + (u32)(j + 128*q);
  float xc  = (float)__builtin_bit_cast(f16, xp[0]) + bb;
  float xn1 = (T_STEPS > 1) ? (float)__builtin_bit_cast(f16, xp[131072u]) + bb : 0.f;

  for (int s = 0; s < T_STEPS; ++s){
    const char* hq = hbuf[s & 1] + q * HQ_STRIDE;

    float xn2 = 0.f;
    if (s + 2 < T_STEPS)
      xn2 = (float)__builtin_bit_cast(f16, xp[(u32)(s+2) * 131072u]) + bb;

    float p0 = 0.f, p1 = 0.f, p2 = 0.f, p3 = 0.f;
#pragma unroll
    for (int it = 0; it < 4; ++it){
      u32x4 hh = *(const u32x4*)(hq + it*16);    // 4 distinct addrs/wave, bank-disjoint
#pragma unroll
      for (int z = 0; z < 4; ++z){
        p0 = dot2f(hh[z], wg0[4*it+z], p0);
        p1 = dot2f(hh[z], wg1[4*it+z], p1);
        p2 = dot2f(hh[z], wg2[4*it+z], p2);
        p3 = dot2f(hh[z], wg3[4*it+z], p3);
      }
    }
    // reduce across the 4 partner lanes via DPP quad_perm (VALU, no DS traffic)
    p0 += DPPF(p0, 177);  p1 += DPPF(p1, 177);   // xor 1
    p2 += DPPF(p2, 177);  p3 += DPPF(p3, 177);
    p0 += DPPF(p0, 78);   p1 += DPPF(p1, 78);    // xor 2
    p2 += DPPF(p2, 78);   p3 += DPPF(p3, 78);

    // this lane activates gate q of col j: mul -> exp -> add -> rcp -> fma
    float gsum = (q == 0) ? p0 : (q == 1) ? p1 : (q == 2) ? p2 : p3;
    float gval = gsum + xc;
    float r    = rcpraw(1.0f + exp2raw(kexp * gval));
    float av   = fmaf(postm, r, posta);

    // gather the 4 activated gates from partner lanes (DPP quad broadcasts)
    float ai = DPPF(av, 0);     // lane lbase+0
    float af = DPPF(av, 85);    // lane lbase+1
    float ag = DPPF(av, 170);   // lane lbase+2
    float ao = DPPF(av, 255);   // lane lbase+3

    cs = af * cs + ai * ag;
    hv = ao * tanhfast(cs);
    if (q == 0)
      *(u16*)(hbuf[(s & 1) ^ 1] + HW_OFF(j)) = __builtin_bit_cast(u16, (f16)hv);
    __syncthreads();                 // h[s+1] visible; prior-buffer reads all done
    xc = xn1; xn1 = xn2;
  }

  if (q == 0){                       // exact fp32 state out
    out[OUT_HT + b*HID + j] = hv;
    out[OUT_CT + b*HID + j] = cs;
    hf[j] = hv;
  }
  __syncthreads();

  if (t < 256){ // heads hidden, fp32: t<128 -> actor col t; else critic col t-128
    const float* W = (t < HID) ? Wa1 : Wc1;
    const int col  = t & (HID - 1);
    const f32x4* hp4 = (const f32x4*)hf;
    float a0 = 0.f, a1 = 0.f, a2 = 0.f, a3 = 0.f;
#pragma unroll
    for (int qq = 0; qq < 32; ++qq){
      f32x4 hh = hp4[qq];
      a0 = fmaf(hh.x, W[(u32)(4*qq+0)*HID + col], a0);
      a1 = fmaf(hh.y, W[(u32)(4*qq+1)*HID + col], a1);
      a2 = fmaf(hh.z, W[(u32)(4*qq+2)*HID + col], a2);
      a3 = fmaf(hh.w, W[(u32)(4*qq+3)*HID + col], a3);
    }
    float a = (a0 + a1) + (a2 + a3);
    hid[t] = (t < HID) ? tanhfast(a + ba1[col]) : tanhfast(a + bc1[col]);
  }
  __syncthreads();

  {
    const int wv = t >> 6, lane = t & 63;
    float p = 0.f;
    if (wv == 0)      p = hid[lane]     * Wa2[lane*2]   + hid[lane+64]     * Wa2[(lane+64)*2];
    else if (wv == 1) p = hid[lane]     * Wa2[lane*2+1] + hid[lane+64]     * Wa2[(lane+64)*2+1];
    else if (wv == 2) p = hid[128+lane] * Wc2[lane]     + hid[128+lane+64] * Wc2[lane+64];
#pragma unroll
    for (int off = 32; off > 0; off >>= 1) p += __shfl_down(p, off);
    if (lane == 0){
      if (wv == 0) out[b*2 + 0]   = p + ba2[0];
      if (wv == 1) out[b*2 + 1]   = p + ba2[1];
      if (wv == 2) out[OUT_VAL+b] = p + bc2[0];
    }
    if (b == 0 && wv == 3 && lane < 2) out[OUT_STD + lane] = expf(log_std[lane]);
  }
}

extern "C" void kernel_launch(void* const* d_in, const int* in_sizes, int n_in,
                              void* d_out, int out_size, void* d_ws, size_t ws_size,
                              hipStream_t stream)
{
  (void)in_sizes; (void)n_in; (void)out_size; (void)ws_size;
  const float* x    = (const float*)d_in[0];
  const float* h0   = (const float*)d_in[1];
  const float* c0   = (const float*)d_in[2];
  const float* Wx   = (const float*)d_in[3];
  const float* Wh   = (const float*)d_in[4];
  const float* bv   = (const float*)d_in[5];
  const float* Wa1  = (const float*)d_in[6];
  const float* ba1  = (const float*)d_in[7];
  const float* Wa2  = (const float*)d_in[8];
  const float* ba2  = (const float*)d_in[9];
  const float* lstd = (const float*)d_in[10];
  const float* Wc1  = (const float*)d_in[11];
  const float* bc1  = (const float*)d_in[12];
  const float* Wc2  = (const float*)d_in[13];
  const float* bc2  = (const float*)d_in[14];
  float* out = (float*)d_out;
  char*  ws  = (char*)d_ws;

  u16* xw  = (u16*)(ws + XW_OFF);
  u16* wxt = (u16*)(ws + WXT_OFF);

  k_pack_wxt<<<dim3(512),  dim3(256), 0, stream>>>(Wx, wxt);
  k_gemm<<<dim3(2048),     dim3(256), 0, stream>>>(x, wxt, xw);
  k_rnn<<<dim3(256),       dim3(512), 0, stream>>>(xw, Wh, h0, c0, bv,
                                                   Wa1, ba1, Wa2, ba2, Wc1, bc1, Wc2, bc2,
                                                   lstd, out);
}